// Round 11
// baseline (2078.374 us; speedup 1.0000x reference)
//
#include <hip/hip_runtime.h>
#include <hip/hip_bf16.h>
#include <math.h>

#define T_SEQ 512
#define BATCH 64
#define DIN   128
#define H     160
#define G3    480   // 3*H

typedef _Float16 half8_t __attribute__((ext_vector_type(8)));
typedef _Float16 half4_t __attribute__((ext_vector_type(4)));
typedef _Float16 half2_t __attribute__((ext_vector_type(2)));
typedef float    f32x4   __attribute__((ext_vector_type(4)));

__device__ __forceinline__ float sigmoidf_(float x) {
    return 1.0f / (1.0f + __expf(-x));
}
__device__ __forceinline__ float tanhf_(float x) {
    float a = fabsf(x);
    float e = __expf(2.0f * a);
    float t = 1.0f - 2.0f / (e + 1.0f);
    return copysignf(t, x);
}

// 8-element f16 dot, f32 accumulate into 4 independent accumulators.
__device__ __forceinline__ void dot8(const half8_t h, const half8_t w,
                                     float& a0, float& a1, float& a2, float& a3) {
#if __has_builtin(__builtin_amdgcn_fdot2)
    half2_t h01{h[0], h[1]}, h23{h[2], h[3]}, h45{h[4], h[5]}, h67{h[6], h[7]};
    half2_t w01{w[0], w[1]}, w23{w[2], w[3]}, w45{w[4], w[5]}, w67{w[6], w[7]};
    a0 = __builtin_amdgcn_fdot2(h01, w01, a0, false);
    a1 = __builtin_amdgcn_fdot2(h23, w23, a1, false);
    a2 = __builtin_amdgcn_fdot2(h45, w45, a2, false);
    a3 = __builtin_amdgcn_fdot2(h67, w67, a3, false);
#else
    a0 += (float)h[0] * (float)w[0] + (float)h[1] * (float)w[1];
    a1 += (float)h[2] * (float)w[2] + (float)h[3] * (float)w[3];
    a2 += (float)h[4] * (float)w[4] + (float)h[5] * (float)w[5];
    a3 += (float)h[6] * (float)w[6] + (float)h[7] * (float)w[7];
#endif
}

// ---------------- block reductions ----------------
__device__ __forceinline__ float blockReduceSum(float v, float* red) {
    #pragma unroll
    for (int off = 32; off > 0; off >>= 1) v += __shfl_down(v, off, 64);
    int wave = threadIdx.x >> 6, lane = threadIdx.x & 63;
    __syncthreads();
    if (lane == 0) red[wave] = v;
    __syncthreads();
    float s = red[0];
    int nw = blockDim.x >> 6;
    for (int i = 1; i < nw; ++i) s += red[i];
    return s;
}
__device__ __forceinline__ float blockReduceMax(float v, float* red) {
    #pragma unroll
    for (int off = 32; off > 0; off >>= 1) v = fmaxf(v, __shfl_down(v, off, 64));
    int wave = threadIdx.x >> 6, lane = threadIdx.x & 63;
    __syncthreads();
    if (lane == 0) red[wave] = v;
    __syncthreads();
    float s = red[0];
    int nw = blockDim.x >> 6;
    for (int i = 1; i < nw; ++i) s = fmaxf(s, red[i]);
    return s;
}

// ---------------- f32 -> f16 conversion, vectorized x4, grid-stride ----------
__global__ __launch_bounds__(256) void cvt_f2h_kernel(
    const float* __restrict__ src, _Float16* __restrict__ dst, int n4)
{
    int i = blockIdx.x * 256 + threadIdx.x;
    int stride = gridDim.x * 256;
    for (; i < n4; i += stride) {
        float4 v = reinterpret_cast<const float4*>(src)[i];
        half4_t h = {(_Float16)v.x, (_Float16)v.y, (_Float16)v.z, (_Float16)v.w};
        reinterpret_cast<half4_t*>(dst)[i] = h;
    }
}

// ---------------- f16 MFMA GEMM: C[M,N] = A[M,K] . B[N,K]^T + bias ----------
// (unchanged from round 8 -- verified, absmax 9.8e-4)
template<int LDSK>
__global__ __launch_bounds__(256) void gemm_f16_mfma_kernel(
    const _Float16* __restrict__ A, const _Float16* __restrict__ B,
    const float* __restrict__ bias, float* __restrict__ C,
    int N, int K, int act)
{
    __shared__ _Float16 Bs[64][LDSK];
    int tid  = threadIdx.x;
    int lane = tid & 63, wave = tid >> 6;
    int row0 = blockIdx.x * 64, col0 = blockIdx.y * 64;
    int kc8 = K >> 3;
    for (int idx = tid; idx < 64 * kc8; idx += 256) {
        int rr = idx / kc8, kc = (idx - rr * kc8) << 3;
        int gcol = col0 + rr;
        half8_t v = {};
        if (gcol < N) v = *reinterpret_cast<const half8_t*>(B + (size_t)gcol * K + kc);
        *reinterpret_cast<half8_t*>(&Bs[rr][kc]) = v;
    }
    __syncthreads();

    f32x4 acc0 = {}, acc1 = {}, acc2 = {}, acc3 = {};
    int arow = row0 + wave * 16 + (lane & 15);
    int koff = (lane >> 4) << 3;
    const _Float16* ap = A + (size_t)arow * K + koff;
    int bl = lane & 15;
    for (int k0 = 0; k0 < K; k0 += 32) {
        half8_t a8 = *reinterpret_cast<const half8_t*>(ap + k0);
        half8_t b0 = *reinterpret_cast<const half8_t*>(&Bs[bl     ][k0 + koff]);
        half8_t b1 = *reinterpret_cast<const half8_t*>(&Bs[bl + 16][k0 + koff]);
        half8_t b2 = *reinterpret_cast<const half8_t*>(&Bs[bl + 32][k0 + koff]);
        half8_t b3 = *reinterpret_cast<const half8_t*>(&Bs[bl + 48][k0 + koff]);
        acc0 = __builtin_amdgcn_mfma_f32_16x16x32_f16(a8, b0, acc0, 0, 0, 0);
        acc1 = __builtin_amdgcn_mfma_f32_16x16x32_f16(a8, b1, acc1, 0, 0, 0);
        acc2 = __builtin_amdgcn_mfma_f32_16x16x32_f16(a8, b2, acc2, 0, 0, 0);
        acc3 = __builtin_amdgcn_mfma_f32_16x16x32_f16(a8, b3, acc3, 0, 0, 0);
    }

    int crow = row0 + wave * 16 + ((lane >> 4) << 2);
    int cb   = col0 + (lane & 15);
    f32x4 accs[4] = {acc0, acc1, acc2, acc3};
    #pragma unroll
    for (int j = 0; j < 4; ++j) {
        int ccol = cb + j * 16;
        if (ccol < N) {
            float bv = bias[ccol];
            #pragma unroll
            for (int i = 0; i < 4; ++i) {
                float v = accs[j][i] + bv;
                if (act) v = tanhf_(v);
                C[(size_t)(crow + i) * N + ccol] = v;
            }
        }
    }
}

// ---------------- GRU recurrence: one block per batch, BOTH dirs ------------
// R7-R9: step time ~2000 cyc invariant under wave count / LDS reads / weight
// pinning; VALU issue only ~300 cyc/step. => serial LATENCY chain per step.
// Fix (TLP): 1024 threads, waves 0-7 run dir0 (1 row/thread), waves 8-15 run
// dir1. Two independent recurrences per CU hide each other's exposed latency.
// R10's NaN post-mortem: volatile-asm weight pinning can be spilled by regalloc
// BETWEEN load-issue and vmcnt wait -> garbage spill. R7 proved pinning is
// perf-neutral anyway (pinned 52-VGPR == streamed 36-VGPR time), so use PLAIN
// loads and let the compiler manage residency/waitcnts.
// xw: [B][T][960] f32, whh_h: [2][480][160] f16, bhh: [2][480] f32,
// out: [B][T][320] f16 (dir0 -> 0..159, dir1 -> 160..319)
__global__ __launch_bounds__(1024) void gru_kernel(
    const float* __restrict__ xw, const _Float16* __restrict__ whh_h,
    const float* __restrict__ bhh, _Float16* __restrict__ out)
{
    int b    = blockIdx.x;
    int tid  = threadIdx.x;
    int dir  = tid >> 9;          // waves 0-7: dir0, waves 8-15: dir1
    int l    = tid & 511;
    bool rowact = (l < G3);
    int rc   = rowact ? l : 0;
    bool gact = (l < H);
    __shared__ __align__(16) _Float16 h_h[2][H];
    __shared__ float g_s[2][G3];

    const half8_t* wp8 = reinterpret_cast<const half8_t*>(
        whh_h + ((size_t)dir * G3 + rc) * H);
    half8_t w0  = wp8[0],  w1  = wp8[1],  w2  = wp8[2],  w3  = wp8[3];
    half8_t w4  = wp8[4],  w5  = wp8[5],  w6  = wp8[6],  w7  = wp8[7];
    half8_t w8  = wp8[8],  w9  = wp8[9],  w10 = wp8[10], w11 = wp8[11];
    half8_t w12 = wp8[12], w13 = wp8[13], w14 = wp8[14], w15 = wp8[15];
    half8_t w16 = wp8[16], w17 = wp8[17], w18 = wp8[18], w19 = wp8[19];
    float bias = bhh[dir * G3 + rc];

    if (gact) h_h[dir][l] = (_Float16)0.f;
    float hcur = 0.f;
    __syncthreads();

    // preload xw for step 0
    float xr = 0.f, xz = 0.f, xn = 0.f;
    {
        int tt0 = dir ? (T_SEQ - 1) : 0;
        size_t base0 = ((size_t)b * T_SEQ + tt0) * 960 + (size_t)dir * G3;
        if (gact) {
            xr = xw[base0 + l];
            xz = xw[base0 + H + l];
            xn = xw[base0 + 2 * H + l];
        }
    }

    for (int step = 0; step < T_SEQ; ++step) {
        int tt = dir ? (T_SEQ - 1 - step) : step;
        // prefetch step+1's xW (HBM latency hides under this step)
        float nxr = 0.f, nxz = 0.f, nxn = 0.f;
        {
            int sn  = (step + 1 < T_SEQ) ? step + 1 : step;
            int ttn = dir ? (T_SEQ - 1 - sn) : sn;
            size_t basen = ((size_t)b * T_SEQ + ttn) * 960 + (size_t)dir * G3;
            if (gact) {
                nxr = xw[basen + l];
                nxz = xw[basen + H + l];
                nxn = xw[basen + 2 * H + l];
            }
        }
        // 160-long dot: 80 v_dot2, 4 ILP accumulators. Whole wave is one dir
        // -> all lanes read the same h address (broadcast, conflict-free).
        float a0 = 0.f, a1 = 0.f, a2 = 0.f, a3 = 0.f;
        {
            const half8_t* hp8 = reinterpret_cast<const half8_t*>(&h_h[dir][0]);
            dot8(hp8[0],  w0,  a0, a1, a2, a3);
            dot8(hp8[1],  w1,  a0, a1, a2, a3);
            dot8(hp8[2],  w2,  a0, a1, a2, a3);
            dot8(hp8[3],  w3,  a0, a1, a2, a3);
            dot8(hp8[4],  w4,  a0, a1, a2, a3);
            dot8(hp8[5],  w5,  a0, a1, a2, a3);
            dot8(hp8[6],  w6,  a0, a1, a2, a3);
            dot8(hp8[7],  w7,  a0, a1, a2, a3);
            dot8(hp8[8],  w8,  a0, a1, a2, a3);
            dot8(hp8[9],  w9,  a0, a1, a2, a3);
            dot8(hp8[10], w10, a0, a1, a2, a3);
            dot8(hp8[11], w11, a0, a1, a2, a3);
            dot8(hp8[12], w12, a0, a1, a2, a3);
            dot8(hp8[13], w13, a0, a1, a2, a3);
            dot8(hp8[14], w14, a0, a1, a2, a3);
            dot8(hp8[15], w15, a0, a1, a2, a3);
            dot8(hp8[16], w16, a0, a1, a2, a3);
            dot8(hp8[17], w17, a0, a1, a2, a3);
            dot8(hp8[18], w18, a0, a1, a2, a3);
            dot8(hp8[19], w19, a0, a1, a2, a3);
        }
        if (rowact) g_s[dir][l] = (a0 + a1) + (a2 + a3) + bias;
        __syncthreads();
        if (gact) {
            float rg = sigmoidf_(xr + g_s[dir][l]);
            float z  = sigmoidf_(xz + g_s[dir][H + l]);
            float n  = tanhf_(xn + rg * g_s[dir][2 * H + l]);
            float hn = (1.0f - z) * n + z * hcur;
            hcur = hn;
            h_h[dir][l] = (_Float16)hn;
            out[((size_t)b * T_SEQ + tt) * 320 + (size_t)dir * H + l] = (_Float16)hn;
        }
        __syncthreads();
        xr = nxr; xz = nxz; xn = nxn;
    }
}

// ---------------- attn logits: [32768][4] = keys[tok][160] . score_w[h][160] + b ---
__global__ __launch_bounds__(256) void logits_kernel(
    const float* __restrict__ keys, const float* __restrict__ sw,
    const float* __restrict__ sb, float* __restrict__ out)
{
    int gid = blockIdx.x * 256 + threadIdx.x;
    int tok = gid >> 2, h = gid & 3;
    const float4* kr = reinterpret_cast<const float4*>(keys + (size_t)tok * H);
    const float4* wr = reinterpret_cast<const float4*>(sw + (size_t)h * H);
    float acc = 0.f;
    #pragma unroll
    for (int i = 0; i < H / 4; ++i) {
        float4 a = kr[i], w4 = wr[i];
        acc += a.x * w4.x + a.y * w4.y + a.z * w4.z + a.w * w4.w;
    }
    out[gid] = acc + sb[h];
}

// ---------------- epilogue: motion + softmax + pool + proj + LN + L2, 1 block/batch --
__global__ __launch_bounds__(512) void final_kernel(
    const float* __restrict__ x, const float* __restrict__ logits,
    const _Float16* __restrict__ seq, const float* __restrict__ proj_w,
    const float* __restrict__ proj_b, const float* __restrict__ ln_g,
    const float* __restrict__ ln_b, float* __restrict__ out)
{
    int b   = blockIdx.x;
    int tid = threadIdx.x;
    __shared__ float ms[T_SEQ];
    __shared__ float ss[T_SEQ];
    __shared__ __align__(16) float pooled[320];
    __shared__ float red[8];

    // Phase A: motion[t] = ||x[t]-x[t-1]||, m[0]=m[1]; standardize (ddof=1)
    {
        float m = 0.f;
        if (tid >= 1) {
            const float4* xc = reinterpret_cast<const float4*>(x + ((size_t)b * T_SEQ + tid) * DIN);
            const float4* xp = reinterpret_cast<const float4*>(x + ((size_t)b * T_SEQ + tid - 1) * DIN);
            float s = 0.f;
            #pragma unroll
            for (int i = 0; i < DIN / 4; ++i) {
                float4 a = xc[i], p = xp[i];
                float dx = a.x - p.x, dy = a.y - p.y, dz = a.z - p.z, dw = a.w - p.w;
                s += dx * dx + dy * dy + dz * dz + dw * dw;
            }
            m = sqrtf(s);
        }
        ms[tid] = m;
    }
    __syncthreads();
    if (tid == 0) ms[0] = ms[1];
    __syncthreads();
    float mv   = ms[tid];
    float mean = blockReduceSum(mv, red) * (1.0f / T_SEQ);
    float var  = blockReduceSum((mv - mean) * (mv - mean), red) * (1.0f / (T_SEQ - 1));
    float mstd = (mv - mean) / (sqrtf(var) + 1e-6f);

    // Phase B: 4 softmaxes over t; s[t] = mean_h weights
    float4 lg = *reinterpret_cast<const float4*>(logits + ((size_t)b * T_SEQ + tid) * 4);
    float l[4] = {lg.x + mstd, lg.y + mstd, lg.z + mstd, lg.w + mstd};
    float ssum = 0.f;
    #pragma unroll
    for (int h = 0; h < 4; ++h) {
        float mx = blockReduceMax(l[h], red);
        float e  = __expf(l[h] - mx);
        float se = blockReduceSum(e, red);
        float wv = e / se;
        ssum += wv;
    }
    float sv = ssum * 0.25f;
    ss[tid] = sv;
    out[16384 + b * T_SEQ + tid] = sv;   // output 1: weights.mean(axis=2)
    __syncthreads();

    // Phase C: pooled[d] = sum_t seq[b,t,d] * s[t]  (seq is f16)
    if (tid < 320) {
        float acc = 0.f;
        const _Float16* sp = seq + (size_t)b * T_SEQ * 320 + tid;
        #pragma unroll 4
        for (int t = 0; t < T_SEQ; ++t) acc += (float)sp[(size_t)t * 320] * ss[t];
        pooled[tid] = acc;
    }
    __syncthreads();

    // Phase D: embedding = pooled . proj_w^T + b ; LN ; L2-normalize
    float e = 0.f;
    if (tid < 256) {
        const float4* pw = reinterpret_cast<const float4*>(proj_w + (size_t)tid * 320);
        const float4* pl = reinterpret_cast<const float4*>(pooled);
        float acc = 0.f;
        #pragma unroll
        for (int i = 0; i < 80; ++i) {
            float4 w4 = pw[i], p4 = pl[i];
            acc += w4.x * p4.x + w4.y * p4.y + w4.z * p4.z + w4.w * p4.w;
        }
        e = acc + proj_b[tid];
    }
    float mu = blockReduceSum(tid < 256 ? e : 0.f, red) * (1.0f / 256);
    float dv = (tid < 256) ? (e - mu) : 0.f;
    float vr = blockReduceSum(dv * dv, red) * (1.0f / 256);
    float g  = 0.f;
    if (tid < 256) g = (e - mu) * rsqrtf(vr + 1e-5f) * ln_g[tid] + ln_b[tid];
    float nrm = sqrtf(blockReduceSum(g * g, red));
    nrm = fmaxf(nrm, 1e-12f);
    if (tid < 256) out[b * 256 + tid] = g / nrm;
}

extern "C" void kernel_launch(void* const* d_in, const int* in_sizes, int n_in,
                              void* d_out, int out_size, void* d_ws, size_t ws_size,
                              hipStream_t stream) {
    const float* x       = (const float*)d_in[0];
    const float* Wih0    = (const float*)d_in[1];
    const float* Whh0    = (const float*)d_in[2];
    const float* bih0    = (const float*)d_in[3];
    const float* bhh0    = (const float*)d_in[4];
    const float* Wih1    = (const float*)d_in[5];
    const float* Whh1    = (const float*)d_in[6];
    const float* bih1    = (const float*)d_in[7];
    const float* bhh1    = (const float*)d_in[8];
    const float* key_w   = (const float*)d_in[9];
    const float* key_b   = (const float*)d_in[10];
    const float* score_w = (const float*)d_in[11];
    const float* score_b = (const float*)d_in[12];
    const float* proj_w  = (const float*)d_in[13];
    const float* proj_b  = (const float*)d_in[14];
    const float* ln_g    = (const float*)d_in[15];
    const float* ln_b    = (const float*)d_in[16];

    const int M  = BATCH * T_SEQ;             // 32768
    const int NW = 2 * G3 * H;                // 153600 per GRU layer

    float* ws    = (float*)d_ws;
    float* xwbuf = ws;                        // 31457280 f
    float* keys  = xwbuf + 31457280;          //  5242880 f
    float* lgts  = keys + 5242880;            //   131072 f
    _Float16* h1_h   = (_Float16*)(lgts + 131072);   // 10485760 h = 5242880 f
    _Float16* seq_h  = h1_h + 10485760;              // 10485760 h
    _Float16* x_h    = seq_h + 10485760;             //  4194304 h
    _Float16* whh_h  = x_h + 4194304;                //   307200 h (both layers)
    _Float16* wih0_h = whh_h + 2 * NW;               //   122880 h
    _Float16* wih1_h = wih0_h + 122880;              //   307200 h
    _Float16* keyw_h = wih1_h + 307200;              //    51200 h
    float* outf  = (float*)d_out;

    // f32 -> f16 conversions (weights + x), all independent
    cvt_f2h_kernel<<<150, 256, 0, stream>>>(Whh0, whh_h, NW / 4);
    cvt_f2h_kernel<<<150, 256, 0, stream>>>(Whh1, whh_h + NW, NW / 4);
    cvt_f2h_kernel<<<120, 256, 0, stream>>>(Wih0, wih0_h, 122880 / 4);
    cvt_f2h_kernel<<<300, 256, 0, stream>>>(Wih1, wih1_h, 307200 / 4);
    cvt_f2h_kernel<<<50,  256, 0, stream>>>(key_w, keyw_h, 51200 / 4);
    cvt_f2h_kernel<<<2048, 256, 0, stream>>>(x, x_h, 4194304 / 4);

    gemm_f16_mfma_kernel<144><<<dim3(M / 64, 15), 256, 0, stream>>>(
        x_h, wih0_h, bih0, xwbuf, 960, 128, 0);
    gru_kernel<<<64, 1024, 0, stream>>>(xwbuf, whh_h, bhh0, h1_h);
    gemm_f16_mfma_kernel<336><<<dim3(M / 64, 15), 256, 0, stream>>>(
        h1_h, wih1_h, bih1, xwbuf, 960, 320, 0);
    gru_kernel<<<64, 1024, 0, stream>>>(xwbuf, whh_h + NW, bhh1, seq_h);
    gemm_f16_mfma_kernel<336><<<dim3(M / 64, 3), 256, 0, stream>>>(
        seq_h, keyw_h, key_b, keys, 160, 320, 1);
    logits_kernel<<<512, 256, 0, stream>>>(keys, score_w, score_b, lgts);
    final_kernel<<<64, 512, 0, stream>>>(x, lgts, seq_h, proj_w, proj_b, ln_g, ln_b, outf);
}

// Round 13
// 1339.834 us; speedup vs baseline: 1.5512x; 1.5512x over previous
//
#include <hip/hip_runtime.h>
#include <hip/hip_bf16.h>
#include <math.h>

#define T_SEQ 512
#define BATCH 64
#define DIN   128
#define H     160
#define G3    480   // 3*H

typedef _Float16 half8_t __attribute__((ext_vector_type(8)));
typedef _Float16 half4_t __attribute__((ext_vector_type(4)));
typedef _Float16 half2_t __attribute__((ext_vector_type(2)));
typedef float    f32x4   __attribute__((ext_vector_type(4)));

__device__ __forceinline__ float sigmoidf_(float x) {
    return 1.0f / (1.0f + __expf(-x));
}
__device__ __forceinline__ float tanhf_(float x) {
    float a = fabsf(x);
    float e = __expf(2.0f * a);
    float t = 1.0f - 2.0f / (e + 1.0f);
    return copysignf(t, x);
}

__device__ __forceinline__ float fdot2_(half2_t a, half2_t b, float c) {
#if __has_builtin(__builtin_amdgcn_fdot2)
    return __builtin_amdgcn_fdot2(a, b, c, false);
#else
    return c + (float)a[0] * (float)b[0] + (float)a[1] * (float)b[1];
#endif
}

// one 8-chunk of h against the three gate weight rows; 2 accumulators/gate.
__device__ __forceinline__ void dot8_g(const half8_t h, const half8_t wr,
                                       const half8_t wz, const half8_t wn,
                                       float& ar0, float& ar1, float& az0, float& az1,
                                       float& an0, float& an1) {
    half2_t h01{h[0], h[1]}, h23{h[2], h[3]}, h45{h[4], h[5]}, h67{h[6], h[7]};
    ar0 = fdot2_(h01, half2_t{wr[0], wr[1]}, ar0);
    ar1 = fdot2_(h23, half2_t{wr[2], wr[3]}, ar1);
    ar0 = fdot2_(h45, half2_t{wr[4], wr[5]}, ar0);
    ar1 = fdot2_(h67, half2_t{wr[6], wr[7]}, ar1);
    az0 = fdot2_(h01, half2_t{wz[0], wz[1]}, az0);
    az1 = fdot2_(h23, half2_t{wz[2], wz[3]}, az1);
    az0 = fdot2_(h45, half2_t{wz[4], wz[5]}, az0);
    az1 = fdot2_(h67, half2_t{wz[6], wz[7]}, az1);
    an0 = fdot2_(h01, half2_t{wn[0], wn[1]}, an0);
    an1 = fdot2_(h23, half2_t{wn[2], wn[3]}, an1);
    an0 = fdot2_(h45, half2_t{wn[4], wn[5]}, an0);
    an1 = fdot2_(h67, half2_t{wn[6], wn[7]}, an1);
}

// ---------------- block reductions ----------------
__device__ __forceinline__ float blockReduceSum(float v, float* red) {
    #pragma unroll
    for (int off = 32; off > 0; off >>= 1) v += __shfl_down(v, off, 64);
    int wave = threadIdx.x >> 6, lane = threadIdx.x & 63;
    __syncthreads();
    if (lane == 0) red[wave] = v;
    __syncthreads();
    float s = red[0];
    int nw = blockDim.x >> 6;
    for (int i = 1; i < nw; ++i) s += red[i];
    return s;
}
__device__ __forceinline__ float blockReduceMax(float v, float* red) {
    #pragma unroll
    for (int off = 32; off > 0; off >>= 1) v = fmaxf(v, __shfl_down(v, off, 64));
    int wave = threadIdx.x >> 6, lane = threadIdx.x & 63;
    __syncthreads();
    if (lane == 0) red[wave] = v;
    __syncthreads();
    float s = red[0];
    int nw = blockDim.x >> 6;
    for (int i = 1; i < nw; ++i) s = fmaxf(s, red[i]);
    return s;
}

// ---------------- f32 -> f16 conversion, vectorized x4, grid-stride ----------
__global__ __launch_bounds__(256) void cvt_f2h_kernel(
    const float* __restrict__ src, _Float16* __restrict__ dst, int n4)
{
    int i = blockIdx.x * 256 + threadIdx.x;
    int stride = gridDim.x * 256;
    for (; i < n4; i += stride) {
        float4 v = reinterpret_cast<const float4*>(src)[i];
        half4_t h = {(_Float16)v.x, (_Float16)v.y, (_Float16)v.z, (_Float16)v.w};
        reinterpret_cast<half4_t*>(dst)[i] = h;
    }
}

// ---------------- Whh f32 -> f16 with gate-interleave permutation ------------
// src: [2][3H][H] (dir, j*H+l, k)  ->  dst: [2][480][H] with newrow = 3l+j.
// Thread (l,kq) then reads rows 3l,3l+1,3l+2 = r,z,n for unit l contiguously.
__global__ __launch_bounds__(256) void cvt_whh_kernel(
    const float* __restrict__ src, _Float16* __restrict__ dst)
{
    int i = blockIdx.x * 256 + threadIdx.x;          // over 2*G3*H = 153600
    if (i >= 2 * G3 * H) return;
    int dir = i / (G3 * H);
    int rem = i - dir * (G3 * H);
    int nr  = rem / H;
    int k   = rem - nr * H;
    int l   = nr / 3;
    int j   = nr - l * 3;
    dst[i] = (_Float16)src[(size_t)dir * G3 * H + ((size_t)j * H + l) * H + k];
}

// ---------------- f16 MFMA GEMM: C[M,N] = A[M,K] . B[N,K]^T + bias ----------
// (unchanged from round 8 -- verified, absmax 9.8e-4)
template<int LDSK>
__global__ __launch_bounds__(256) void gemm_f16_mfma_kernel(
    const _Float16* __restrict__ A, const _Float16* __restrict__ B,
    const float* __restrict__ bias, float* __restrict__ C,
    int N, int K, int act)
{
    __shared__ _Float16 Bs[64][LDSK];
    int tid  = threadIdx.x;
    int lane = tid & 63, wave = tid >> 6;
    int row0 = blockIdx.x * 64, col0 = blockIdx.y * 64;
    int kc8 = K >> 3;
    for (int idx = tid; idx < 64 * kc8; idx += 256) {
        int rr = idx / kc8, kc = (idx - rr * kc8) << 3;
        int gcol = col0 + rr;
        half8_t v = {};
        if (gcol < N) v = *reinterpret_cast<const half8_t*>(B + (size_t)gcol * K + kc);
        *reinterpret_cast<half8_t*>(&Bs[rr][kc]) = v;
    }
    __syncthreads();

    f32x4 acc0 = {}, acc1 = {}, acc2 = {}, acc3 = {};
    int arow = row0 + wave * 16 + (lane & 15);
    int koff = (lane >> 4) << 3;
    const _Float16* ap = A + (size_t)arow * K + koff;
    int bl = lane & 15;
    for (int k0 = 0; k0 < K; k0 += 32) {
        half8_t a8 = *reinterpret_cast<const half8_t*>(ap + k0);
        half8_t b0 = *reinterpret_cast<const half8_t*>(&Bs[bl     ][k0 + koff]);
        half8_t b1 = *reinterpret_cast<const half8_t*>(&Bs[bl + 16][k0 + koff]);
        half8_t b2 = *reinterpret_cast<const half8_t*>(&Bs[bl + 32][k0 + koff]);
        half8_t b3 = *reinterpret_cast<const half8_t*>(&Bs[bl + 48][k0 + koff]);
        acc0 = __builtin_amdgcn_mfma_f32_16x16x32_f16(a8, b0, acc0, 0, 0, 0);
        acc1 = __builtin_amdgcn_mfma_f32_16x16x32_f16(a8, b1, acc1, 0, 0, 0);
        acc2 = __builtin_amdgcn_mfma_f32_16x16x32_f16(a8, b2, acc2, 0, 0, 0);
        acc3 = __builtin_amdgcn_mfma_f32_16x16x32_f16(a8, b3, acc3, 0, 0, 0);
    }

    int crow = row0 + wave * 16 + ((lane >> 4) << 2);
    int cb   = col0 + (lane & 15);
    f32x4 accs[4] = {acc0, acc1, acc2, acc3};
    #pragma unroll
    for (int j = 0; j < 4; ++j) {
        int ccol = cb + j * 16;
        if (ccol < N) {
            float bv = bias[ccol];
            #pragma unroll
            for (int i = 0; i < 4; ++i) {
                float v = accs[j][i] + bv;
                if (act) v = tanhf_(v);
                C[(size_t)(crow + i) * N + ccol] = v;
            }
        }
    }
}

// ---------------- GRU recurrence: one block per (batch, dir) ----------------
// R6-R11 post-mortem: step ~2000 cyc invariant; the cost is the serial chain
// {dot -> g_s write -> barrier -> gate LDS read -> transcendentals -> h write
// -> barrier}, not dot issue (~300 cyc). This version collapses the chain:
//  * Whh gate-interleaved (newrow=3l+j): thread (l,kq), tid=l*4+kq, computes
//    ALL THREE gate dots for unit l over K-range [kq*40,kq*40+40).
//  * 2-hop __shfl_xor butterfly (partners in-wave) -> full 160-sums in every
//    lane; gates computed locally in all 4 partners -> NO g_s round-trip,
//    no 160-thread gate tail.
//  * h double-buffered in LDS -> ONE barrier per step.
// h-reads: 4 distinct 16B addrs/wave (kq*80B) hit disjoint bank groups,
// 16-lane broadcast each -> conflict-free.
// xw: [B][T][960] f32, whh_h: gate-interleaved [2][480][160] f16,
// bhh: [2][480] f32, out: [B][T][320] f16.
__global__ __launch_bounds__(640)
__attribute__((amdgpu_waves_per_eu(2, 3)))
void gru_kernel(
    const float* __restrict__ xw, const _Float16* __restrict__ whh_h,
    const float* __restrict__ bhh, _Float16* __restrict__ out)
{
    int b   = blockIdx.x >> 1;
    int dir = blockIdx.x & 1;
    int tid = threadIdx.x;
    int l   = tid >> 2;           // hidden unit 0..159
    int kq  = tid & 3;            // K-quarter
    __shared__ __align__(16) _Float16 h_h[2][H];

    const _Float16* wb = whh_h + ((size_t)dir * G3 + 3 * (size_t)l) * H + kq * 40;
    const half8_t* wr8 = reinterpret_cast<const half8_t*>(wb);
    const half8_t* wz8 = reinterpret_cast<const half8_t*>(wb + H);
    const half8_t* wn8 = reinterpret_cast<const half8_t*>(wb + 2 * H);
    half8_t wr0 = wr8[0], wr1 = wr8[1], wr2 = wr8[2], wr3 = wr8[3], wr4 = wr8[4];
    half8_t wz0 = wz8[0], wz1 = wz8[1], wz2 = wz8[2], wz3 = wz8[3], wz4 = wz8[4];
    half8_t wn0 = wn8[0], wn1 = wn8[1], wn2 = wn8[2], wn3 = wn8[3], wn4 = wn8[4];
    float br = bhh[dir * G3 + l];
    float bz = bhh[dir * G3 + H + l];
    float bn = bhh[dir * G3 + 2 * H + l];

    if (tid < H) h_h[0][tid] = (_Float16)0.f;
    float hcur = 0.f;             // maintained redundantly in all 4 partners
    __syncthreads();

    // preload xw for step 0 (all 4 partners load the same 3 values)
    float xr, xz, xn;
    {
        int tt0 = dir ? (T_SEQ - 1) : 0;
        size_t base0 = ((size_t)b * T_SEQ + tt0) * 960 + (size_t)dir * G3;
        xr = xw[base0 + l];
        xz = xw[base0 + H + l];
        xn = xw[base0 + 2 * H + l];
    }

    int rb = 0;
    for (int step = 0; step < T_SEQ; ++step) {
        int tt = dir ? (T_SEQ - 1 - step) : step;
        // prefetch step+1's xW (HBM/L2 latency hides under this step)
        float nxr, nxz, nxn;
        {
            int sn  = (step + 1 < T_SEQ) ? step + 1 : step;
            int ttn = dir ? (T_SEQ - 1 - sn) : sn;
            size_t basen = ((size_t)b * T_SEQ + ttn) * 960 + (size_t)dir * G3;
            nxr = xw[basen + l];
            nxz = xw[basen + H + l];
            nxn = xw[basen + 2 * H + l];
        }
        // read this thread's K-quarter of h (5 x ds_read_b128, conflict-free)
        const half8_t* hp8 = reinterpret_cast<const half8_t*>(&h_h[rb][kq * 40]);
        half8_t h0 = hp8[0], h1 = hp8[1], h2 = hp8[2], h3 = hp8[3], h4 = hp8[4];
        // 3 gates x 40 MACs, 6 independent accumulator chains
        float ar0 = 0.f, ar1 = 0.f, az0 = 0.f, az1 = 0.f, an0 = 0.f, an1 = 0.f;
        dot8_g(h0, wr0, wz0, wn0, ar0, ar1, az0, az1, an0, an1);
        dot8_g(h1, wr1, wz1, wn1, ar0, ar1, az0, az1, an0, an1);
        dot8_g(h2, wr2, wz2, wn2, ar0, ar1, az0, az1, an0, an1);
        dot8_g(h3, wr3, wz3, wn3, ar0, ar1, az0, az1, an0, an1);
        dot8_g(h4, wr4, wz4, wn4, ar0, ar1, az0, az1, an0, an1);
        // butterfly across the 4 K-partners (lanes tid^1, tid^2: same wave)
        float ar = ar0 + ar1, az = az0 + az1, an = an0 + an1;
        ar += __shfl_xor(ar, 1); ar += __shfl_xor(ar, 2);
        az += __shfl_xor(az, 1); az += __shfl_xor(az, 2);
        an += __shfl_xor(an, 1); an += __shfl_xor(an, 2);
        // gates (all 4 partners compute identically; hcur kept in sync)
        float rg = sigmoidf_(xr + ar + br);
        float z  = sigmoidf_(xz + az + bz);
        float n  = tanhf_(xn + rg * (an + bn));
        float hn = (1.0f - z) * n + z * hcur;
        hcur = hn;
        if (kq == 0) {
            h_h[rb ^ 1][l] = (_Float16)hn;
            out[((size_t)b * T_SEQ + tt) * 320 + (size_t)dir * H + l] = (_Float16)hn;
        }
        __syncthreads();          // single barrier: write visible before next read
        rb ^= 1;
        xr = nxr; xz = nxz; xn = nxn;
    }
}

// ---------------- attn logits: [32768][4] = keys[tok][160] . score_w[h][160] + b ---
__global__ __launch_bounds__(256) void logits_kernel(
    const float* __restrict__ keys, const float* __restrict__ sw,
    const float* __restrict__ sb, float* __restrict__ out)
{
    int gid = blockIdx.x * 256 + threadIdx.x;
    int tok = gid >> 2, h = gid & 3;
    const float4* kr = reinterpret_cast<const float4*>(keys + (size_t)tok * H);
    const float4* wr = reinterpret_cast<const float4*>(sw + (size_t)h * H);
    float acc = 0.f;
    #pragma unroll
    for (int i = 0; i < H / 4; ++i) {
        float4 a = kr[i], w4 = wr[i];
        acc += a.x * w4.x + a.y * w4.y + a.z * w4.z + a.w * w4.w;
    }
    out[gid] = acc + sb[h];
}

// ---------------- epilogue: motion + softmax + pool + proj + LN + L2, 1 block/batch --
__global__ __launch_bounds__(512) void final_kernel(
    const float* __restrict__ x, const float* __restrict__ logits,
    const _Float16* __restrict__ seq, const float* __restrict__ proj_w,
    const float* __restrict__ proj_b, const float* __restrict__ ln_g,
    const float* __restrict__ ln_b, float* __restrict__ out)
{
    int b   = blockIdx.x;
    int tid = threadIdx.x;
    __shared__ float ms[T_SEQ];
    __shared__ float ss[T_SEQ];
    __shared__ __align__(16) float pooled[320];
    __shared__ float red[8];

    // Phase A: motion[t] = ||x[t]-x[t-1]||, m[0]=m[1]; standardize (ddof=1)
    {
        float m = 0.f;
        if (tid >= 1) {
            const float4* xc = reinterpret_cast<const float4*>(x + ((size_t)b * T_SEQ + tid) * DIN);
            const float4* xp = reinterpret_cast<const float4*>(x + ((size_t)b * T_SEQ + tid - 1) * DIN);
            float s = 0.f;
            #pragma unroll
            for (int i = 0; i < DIN / 4; ++i) {
                float4 a = xc[i], p = xp[i];
                float dx = a.x - p.x, dy = a.y - p.y, dz = a.z - p.z, dw = a.w - p.w;
                s += dx * dx + dy * dy + dz * dz + dw * dw;
            }
            m = sqrtf(s);
        }
        ms[tid] = m;
    }
    __syncthreads();
    if (tid == 0) ms[0] = ms[1];
    __syncthreads();
    float mv   = ms[tid];
    float mean = blockReduceSum(mv, red) * (1.0f / T_SEQ);
    float var  = blockReduceSum((mv - mean) * (mv - mean), red) * (1.0f / (T_SEQ - 1));
    float mstd = (mv - mean) / (sqrtf(var) + 1e-6f);

    // Phase B: 4 softmaxes over t; s[t] = mean_h weights
    float4 lg = *reinterpret_cast<const float4*>(logits + ((size_t)b * T_SEQ + tid) * 4);
    float l[4] = {lg.x + mstd, lg.y + mstd, lg.z + mstd, lg.w + mstd};
    float ssum = 0.f;
    #pragma unroll
    for (int h = 0; h < 4; ++h) {
        float mx = blockReduceMax(l[h], red);
        float e  = __expf(l[h] - mx);
        float se = blockReduceSum(e, red);
        float wv = e / se;
        ssum += wv;
    }
    float sv = ssum * 0.25f;
    ss[tid] = sv;
    out[16384 + b * T_SEQ + tid] = sv;   // output 1: weights.mean(axis=2)
    __syncthreads();

    // Phase C: pooled[d] = sum_t seq[b,t,d] * s[t]  (seq is f16)
    if (tid < 320) {
        float acc = 0.f;
        const _Float16* sp = seq + (size_t)b * T_SEQ * 320 + tid;
        #pragma unroll 4
        for (int t = 0; t < T_SEQ; ++t) acc += (float)sp[(size_t)t * 320] * ss[t];
        pooled[tid] = acc;
    }
    __syncthreads();

    // Phase D: embedding = pooled . proj_w^T + b ; LN ; L2-normalize
    float e = 0.f;
    if (tid < 256) {
        const float4* pw = reinterpret_cast<const float4*>(proj_w + (size_t)tid * 320);
        const float4* pl = reinterpret_cast<const float4*>(pooled);
        float acc = 0.f;
        #pragma unroll
        for (int i = 0; i < 80; ++i) {
            float4 w4 = pw[i], p4 = pl[i];
            acc += w4.x * p4.x + w4.y * p4.y + w4.z * p4.z + w4.w * p4.w;
        }
        e = acc + proj_b[tid];
    }
    float mu = blockReduceSum(tid < 256 ? e : 0.f, red) * (1.0f / 256);
    float dv = (tid < 256) ? (e - mu) : 0.f;
    float vr = blockReduceSum(dv * dv, red) * (1.0f / 256);
    float g  = 0.f;
    if (tid < 256) g = (e - mu) * rsqrtf(vr + 1e-5f) * ln_g[tid] + ln_b[tid];
    float nrm = sqrtf(blockReduceSum(g * g, red));
    nrm = fmaxf(nrm, 1e-12f);
    if (tid < 256) out[b * 256 + tid] = g / nrm;
}

extern "C" void kernel_launch(void* const* d_in, const int* in_sizes, int n_in,
                              void* d_out, int out_size, void* d_ws, size_t ws_size,
                              hipStream_t stream) {
    const float* x       = (const float*)d_in[0];
    const float* Wih0    = (const float*)d_in[1];
    const float* Whh0    = (const float*)d_in[2];
    const float* bih0    = (const float*)d_in[3];
    const float* bhh0    = (const float*)d_in[4];
    const float* Wih1    = (const float*)d_in[5];
    const float* Whh1    = (const float*)d_in[6];
    const float* bih1    = (const float*)d_in[7];
    const float* bhh1    = (const float*)d_in[8];
    const float* key_w   = (const float*)d_in[9];
    const float* key_b   = (const float*)d_in[10];
    const float* score_w = (const float*)d_in[11];
    const float* score_b = (const float*)d_in[12];
    const float* proj_w  = (const float*)d_in[13];
    const float* proj_b  = (const float*)d_in[14];
    const float* ln_g    = (const float*)d_in[15];
    const float* ln_b    = (const float*)d_in[16];

    const int M  = BATCH * T_SEQ;             // 32768
    const int NW = 2 * G3 * H;                // 153600 per GRU layer

    float* ws    = (float*)d_ws;
    float* xwbuf = ws;                        // 31457280 f
    float* keys  = xwbuf + 31457280;          //  5242880 f
    float* lgts  = keys + 5242880;            //   131072 f
    _Float16* h1_h   = (_Float16*)(lgts + 131072);   // 10485760 h
    _Float16* seq_h  = h1_h + 10485760;              // 10485760 h
    _Float16* x_h    = seq_h + 10485760;             //  4194304 h
    _Float16* whh_h  = x_h + 4194304;                //   307200 h (both layers)
    _Float16* wih0_h = whh_h + 2 * NW;               //   122880 h
    _Float16* wih1_h = wih0_h + 122880;              //   307200 h
    _Float16* keyw_h = wih1_h + 307200;              //    51200 h
    float* outf  = (float*)d_out;

    // f32 -> f16 conversions (weights + x); whh gets the gate-interleave
    cvt_whh_kernel<<<(NW + 255) / 256, 256, 0, stream>>>(Whh0, whh_h);
    cvt_whh_kernel<<<(NW + 255) / 256, 256, 0, stream>>>(Whh1, whh_h + NW);
    cvt_f2h_kernel<<<120, 256, 0, stream>>>(Wih0, wih0_h, 122880 / 4);
    cvt_f2h_kernel<<<300, 256, 0, stream>>>(Wih1, wih1_h, 307200 / 4);
    cvt_f2h_kernel<<<50,  256, 0, stream>>>(key_w, keyw_h, 51200 / 4);
    cvt_f2h_kernel<<<2048, 256, 0, stream>>>(x, x_h, 4194304 / 4);

    gemm_f16_mfma_kernel<144><<<dim3(M / 64, 15), 256, 0, stream>>>(
        x_h, wih0_h, bih0, xwbuf, 960, 128, 0);
    gru_kernel<<<128, 640, 0, stream>>>(xwbuf, whh_h, bhh0, h1_h);
    gemm_f16_mfma_kernel<336><<<dim3(M / 64, 15), 256, 0, stream>>>(
        h1_h, wih1_h, bih1, xwbuf, 960, 320, 0);
    gru_kernel<<<128, 640, 0, stream>>>(xwbuf, whh_h + NW, bhh1, seq_h);
    gemm_f16_mfma_kernel<336><<<dim3(M / 64, 3), 256, 0, stream>>>(
        seq_h, keyw_h, key_b, keys, 160, 320, 1);
    logits_kernel<<<512, 256, 0, stream>>>(keys, score_w, score_b, lgts);
    final_kernel<<<64, 512, 0, stream>>>(x, lgts, seq_h, proj_w, proj_b, ln_g, ln_b, outf);
}